// Round 1
// baseline (1260.822 us; speedup 1.0000x reference)
//
#include <hip/hip_runtime.h>
#include <hip/hip_bf16.h>
#include <math.h>

#define T_STEPS 2048
#define B_SZ 8
#define D_SZ 1024
#define M_SZ (T_STEPS * B_SZ)   // 16384 rows (t*B + b)
#define K_SZ D_SZ               // 1024
#define N_SZ (2 * D_SZ)         // 2048 (alpha cols | v cols)

#define BM 128
#define BN 128
#define BK 8

__device__ __forceinline__ float sigmoidf_(float z) {
    return 1.0f / (1.0f + __expf(-z));
}

// C[m][n] = sum_k x[m][k] * W[n][k]  (+bias, sigmoid on alpha half)
// alpha (n<1024)  -> out[m*D + n]                      (output region, scratch)
// v     (n>=1024) -> hbuf[(m+B)*D + (n-1024)]          (h region, slot t+1)
__global__ __launch_bounds__(256) void gemm_gates(
    const float* __restrict__ x,
    const float* __restrict__ Wa,
    const float* __restrict__ ba,
    const float* __restrict__ Wv,
    const float* __restrict__ bv,
    float* __restrict__ out)
{
    __shared__ float sA[BK][BM];
    __shared__ float sB[BK][BN];

    const int m0 = blockIdx.x * BM;
    const int n0 = blockIdx.y * BN;

    const bool is_v = (n0 >= D_SZ);
    const float* W    = is_v ? (Wv + (size_t)(n0 - D_SZ) * K_SZ) : (Wa + (size_t)n0 * K_SZ);
    const float* bias = is_v ? (bv + (n0 - D_SZ)) : (ba + n0);

    const int tid = threadIdx.x;
    const int ty = tid >> 4;      // 0..15 (row group)
    const int tx = tid & 15;      // 0..15 (col group)

    float acc[8][8];
    #pragma unroll
    for (int i = 0; i < 8; ++i)
        #pragma unroll
        for (int j = 0; j < 8; ++j) acc[i][j] = 0.f;

    const int lrow = tid >> 1;        // 0..127
    const int lk   = (tid & 1) * 4;   // 0 or 4

    const float* xrow = x + (size_t)(m0 + lrow) * K_SZ + lk;
    const float* wrow = W + (size_t)lrow * K_SZ + lk;

    for (int k0 = 0; k0 < K_SZ; k0 += BK) {
        const float4 av = *reinterpret_cast<const float4*>(xrow + k0);
        const float4 wv = *reinterpret_cast<const float4*>(wrow + k0);

        __syncthreads();   // previous iteration's reads complete
        sA[lk + 0][lrow] = av.x;
        sA[lk + 1][lrow] = av.y;
        sA[lk + 2][lrow] = av.z;
        sA[lk + 3][lrow] = av.w;
        sB[lk + 0][lrow] = wv.x;
        sB[lk + 1][lrow] = wv.y;
        sB[lk + 2][lrow] = wv.z;
        sB[lk + 3][lrow] = wv.w;
        __syncthreads();

        #pragma unroll
        for (int kk = 0; kk < BK; ++kk) {
            const float4 a0 = *reinterpret_cast<const float4*>(&sA[kk][ty * 8]);
            const float4 a1 = *reinterpret_cast<const float4*>(&sA[kk][ty * 8 + 4]);
            const float4 b0 = *reinterpret_cast<const float4*>(&sB[kk][tx * 8]);
            const float4 b1 = *reinterpret_cast<const float4*>(&sB[kk][tx * 8 + 4]);
            const float a[8] = {a0.x, a0.y, a0.z, a0.w, a1.x, a1.y, a1.z, a1.w};
            const float b[8] = {b0.x, b0.y, b0.z, b0.w, b1.x, b1.y, b1.z, b1.w};
            #pragma unroll
            for (int i = 0; i < 8; ++i)
                #pragma unroll
                for (int j = 0; j < 8; ++j)
                    acc[i][j] = fmaf(a[i], b[j], acc[i][j]);
        }
    }

    // epilogue
    float bj[8];
    #pragma unroll
    for (int j = 0; j < 8; ++j) bj[j] = bias[tx * 8 + j];

    float* hbuf = out + (size_t)M_SZ * D_SZ;

    #pragma unroll
    for (int i = 0; i < 8; ++i) {
        const int m = m0 + ty * 8 + i;
        float* dst;
        if (!is_v) {
            dst = out + (size_t)m * D_SZ + n0 + tx * 8;
        } else {
            dst = hbuf + (size_t)(m + B_SZ) * D_SZ + (n0 - D_SZ) + tx * 8;
        }
        float r[8];
        #pragma unroll
        for (int j = 0; j < 8; ++j) {
            const float z = acc[i][j] + bj[j];
            r[j] = is_v ? z : sigmoidf_(z);
        }
        *reinterpret_cast<float4*>(dst)     = make_float4(r[0], r[1], r[2], r[3]);
        *reinterpret_cast<float4*>(dst + 4) = make_float4(r[4], r[5], r[6], r[7]);
    }
}

// Serial scan over T. alpha region becomes output; hbuf slots t+1 hold v, become h.
__global__ __launch_bounds__(64) void scan_kernel(float* __restrict__ out)
{
    const int gid = blockIdx.x * 64 + threadIdx.x;   // 0..8191 over (b,d)
    float* alpha = out;
    float* hbuf  = out + (size_t)M_SZ * D_SZ;

    hbuf[gid] = 0.f;   // h0 = 0

    const int stride = B_SZ * D_SZ;  // 8192
    float h = 0.f;
    size_t idx = gid;

    // one-step software prefetch
    float a = alpha[idx];
    float v = hbuf[idx + stride];

    for (int t = 0; t < T_STEPS; ++t) {
        float a_n = 0.f, v_n = 0.f;
        if (t + 1 < T_STEPS) {
            a_n = alpha[idx + stride];
            v_n = hbuf[idx + 2 * (size_t)stride];
        }
        h = a * h + v;
        hbuf[idx + stride] = h;
        alpha[idx] = h * h * sigmoidf_(h);
        idx += stride;
        a = a_n;
        v = v_n;
    }
}

extern "C" void kernel_launch(void* const* d_in, const int* in_sizes, int n_in,
                              void* d_out, int out_size, void* d_ws, size_t ws_size,
                              hipStream_t stream) {
    const float* x  = (const float*)d_in[0];
    const float* Wa = (const float*)d_in[1];
    const float* ba = (const float*)d_in[2];
    const float* Wv = (const float*)d_in[3];
    const float* bv = (const float*)d_in[4];
    float* out = (float*)d_out;

    dim3 grid(M_SZ / BM, N_SZ / BN);   // (128, 16)
    gemm_gates<<<grid, 256, 0, stream>>>(x, Wa, ba, Wv, bv, out);
    scan_kernel<<<(B_SZ * D_SZ) / 64, 64, 0, stream>>>(out);
}

// Round 5
// 488.960 us; speedup vs baseline: 2.5786x; 2.5786x over previous
//
#include <hip/hip_runtime.h>
#include <hip/hip_bf16.h>
#include <math.h>

#define T_STEPS 2048
#define B_SZ 8
#define D_SZ 1024
#define M_SZ (T_STEPS * B_SZ)   // 16384 rows (t*B + b)
#define K_SZ D_SZ               // 1024
#define N_SZ (2 * D_SZ)         // 2048 (alpha cols | v cols)

#define BM 128
#define BN 128
#define BK 32
#define LDSS 40                 // LDS row stride in bf16 elements (80 B, 16B-aligned, bank-spread)

typedef __attribute__((ext_vector_type(8))) short bf16x8;
typedef __attribute__((ext_vector_type(4))) float f32x4;

__device__ __forceinline__ float sigmoidf_(float z) {
    return 1.0f / (1.0f + __expf(-z));
}

// round-to-nearest-even fp32 -> bf16, also returns the back-converted fp32
__device__ __forceinline__ ushort bf16_rne(float f, float* back) {
    uint u = __float_as_uint(f);
    uint r = (u + 0x7FFFu + ((u >> 16) & 1u)) >> 16;
    *back = __uint_as_float(r << 16);
    return (ushort)r;
}

// C[m][n] = sum_k x[m][k] * W[n][k] via split-bf16 MFMA (hi*hi + lo*hi + hi*lo).
// alpha (n<1024): sigmoid(.+ba) -> out[m*D + n]
// v (n>=1024):    (.+bv)        -> hbuf[(m+B)*D + (n-1024)]  (h region, slot t+1)
__global__ __launch_bounds__(256) void gemm_gates(
    const float* __restrict__ x,
    const float* __restrict__ Wa,
    const float* __restrict__ ba,
    const float* __restrict__ Wv,
    const float* __restrict__ bv,
    float* __restrict__ out)
{
    __shared__ ushort sAh[BM * LDSS];
    __shared__ ushort sAl[BM * LDSS];
    __shared__ ushort sBh[BN * LDSS];
    __shared__ ushort sBl[BN * LDSS];

    const int m0 = blockIdx.x * BM;
    const int n0 = blockIdx.y * BN;

    const bool is_v = (n0 >= D_SZ);
    const float* W = is_v ? (Wv + (size_t)(n0 - D_SZ) * K_SZ) : (Wa + (size_t)n0 * K_SZ);

    const int tid = threadIdx.x;
    const int wid = tid >> 6;
    const int lane = tid & 63;
    const int wm = wid >> 1;     // wave row (0..1) -> 64 rows
    const int wn = wid & 1;      // wave col (0..1) -> 64 cols
    const int l15 = lane & 15;
    const int l4 = lane >> 4;    // 0..3

    // staging map: thread loads rows r0+32p, cols c4*4..c4*4+3, p=0..3
    const int r0 = tid >> 3;     // 0..31
    const int c4 = tid & 7;      // 0..7

    const float* xp = x + (size_t)(m0 + r0) * K_SZ + c4 * 4;
    const float* wp = W + (size_t)r0 * K_SZ + c4 * 4;

    f32x4 acc[4][4];
    #pragma unroll
    for (int i = 0; i < 4; ++i)
        #pragma unroll
        for (int j = 0; j < 4; ++j)
            acc[i][j] = (f32x4){0.f, 0.f, 0.f, 0.f};

    for (int k0 = 0; k0 < K_SZ; k0 += BK) {
        float4 areg[4], breg[4];
        #pragma unroll
        for (int p = 0; p < 4; ++p) {
            areg[p] = *reinterpret_cast<const float4*>(xp + k0 + (size_t)(32 * p) * K_SZ);
            breg[p] = *reinterpret_cast<const float4*>(wp + k0 + (size_t)(32 * p) * K_SZ);
        }

        __syncthreads();   // previous iteration's LDS reads complete

        #pragma unroll
        for (int p = 0; p < 4; ++p) {
            const int e = (r0 + 32 * p) * LDSS + c4 * 4;
            float bk;
            ushort4 hi, lo;
            float fa[4] = {areg[p].x, areg[p].y, areg[p].z, areg[p].w};
            hi.x = bf16_rne(fa[0], &bk); lo.x = bf16_rne(fa[0] - bk, &bk);
            hi.y = bf16_rne(fa[1], &bk); lo.y = bf16_rne(fa[1] - bk, &bk);
            hi.z = bf16_rne(fa[2], &bk); lo.z = bf16_rne(fa[2] - bk, &bk);
            hi.w = bf16_rne(fa[3], &bk); lo.w = bf16_rne(fa[3] - bk, &bk);
            *reinterpret_cast<ushort4*>(&sAh[e]) = hi;
            *reinterpret_cast<ushort4*>(&sAl[e]) = lo;
            float fb[4] = {breg[p].x, breg[p].y, breg[p].z, breg[p].w};
            hi.x = bf16_rne(fb[0], &bk); lo.x = bf16_rne(fb[0] - bk, &bk);
            hi.y = bf16_rne(fb[1], &bk); lo.y = bf16_rne(fb[1] - bk, &bk);
            hi.z = bf16_rne(fb[2], &bk); lo.z = bf16_rne(fb[2] - bk, &bk);
            hi.w = bf16_rne(fb[3], &bk); lo.w = bf16_rne(fb[3] - bk, &bk);
            *reinterpret_cast<ushort4*>(&sBh[e]) = hi;
            *reinterpret_cast<ushort4*>(&sBl[e]) = lo;
        }

        __syncthreads();

        bf16x8 ah[4], al[4];
        #pragma unroll
        for (int i = 0; i < 4; ++i) {
            const int r = wm * 64 + i * 16 + l15;
            ah[i] = *reinterpret_cast<const bf16x8*>(&sAh[r * LDSS + l4 * 8]);
            al[i] = *reinterpret_cast<const bf16x8*>(&sAl[r * LDSS + l4 * 8]);
        }
        #pragma unroll
        for (int j = 0; j < 4; ++j) {
            const int c = wn * 64 + j * 16 + l15;
            const bf16x8 bh = *reinterpret_cast<const bf16x8*>(&sBh[c * LDSS + l4 * 8]);
            const bf16x8 bl = *reinterpret_cast<const bf16x8*>(&sBl[c * LDSS + l4 * 8]);
            #pragma unroll
            for (int i = 0; i < 4; ++i) {
                acc[i][j] = __builtin_amdgcn_mfma_f32_16x16x32_bf16(ah[i], bh, acc[i][j], 0, 0, 0);
                acc[i][j] = __builtin_amdgcn_mfma_f32_16x16x32_bf16(al[i], bh, acc[i][j], 0, 0, 0);
                acc[i][j] = __builtin_amdgcn_mfma_f32_16x16x32_bf16(ah[i], bl, acc[i][j], 0, 0, 0);
            }
        }
    }

    // epilogue
    float* hbuf = out + (size_t)M_SZ * D_SZ;
    #pragma unroll
    for (int j = 0; j < 4; ++j) {
        const int n = n0 + wn * 64 + j * 16 + l15;           // global n in [0, 2048)
        const float bb = is_v ? bv[n - D_SZ] : ba[n];
        #pragma unroll
        for (int i = 0; i < 4; ++i) {
            const int mb = m0 + wm * 64 + i * 16 + l4 * 4;
            #pragma unroll
            for (int r = 0; r < 4; ++r) {
                const int m = mb + r;
                const float z = acc[i][j][r] + bb;
                if (!is_v) {
                    out[(size_t)m * D_SZ + n] = sigmoidf_(z);
                } else {
                    hbuf[(size_t)(m + B_SZ) * D_SZ + (n - D_SZ)] = z;
                }
            }
        }
    }
}

// Hierarchical scan: block = 1024 threads = 64 chunks x 16 (b,d)-lanes, 512 blocks.
// alpha region -> output, v (h region slots 1..T) -> h in place.
#define SC_LANES 16
#define SC_CHUNKS 64
#define SC_LEN (T_STEPS / SC_CHUNKS)   // 32

__global__ __launch_bounds__(1024) void scan_hier(float* __restrict__ out)
{
    __shared__ float sP[SC_CHUNKS][SC_LANES];
    __shared__ float sQ[SC_CHUNKS][SC_LANES];
    __shared__ float sS[SC_CHUNKS][SC_LANES];

    float* alpha = out;
    float* hbuf = out + (size_t)M_SZ * D_SZ;

    const int tid = threadIdx.x;
    const int c = tid >> 4;        // chunk 0..63
    const int l = tid & 15;        // lane in block
    const int bd = blockIdx.x * SC_LANES + l;
    const int t0 = c * SC_LEN;
    const int STRIDE = B_SZ * D_SZ;   // 8192

    // phase 1: per-chunk (P = prod a, q = local scan from 0)
    float P = 1.f, q = 0.f;
    {
        size_t idx = (size_t)t0 * STRIDE + bd;
        #pragma unroll 4
        for (int s = 0; s < SC_LEN; ++s) {
            const float a = alpha[idx];
            const float v = hbuf[idx + STRIDE];
            q = fmaf(a, q, v);
            P *= a;
            idx += STRIDE;
        }
    }
    sP[c][l] = P;
    sQ[c][l] = q;
    __syncthreads();

    // phase 2: serial combine across chunks (16 threads)
    if (tid < SC_LANES) {
        float s = 0.f;
        #pragma unroll 8
        for (int w = 0; w < SC_CHUNKS; ++w) {
            sS[w][tid] = s;
            s = fmaf(sP[w][tid], s, sQ[w][tid]);
        }
        hbuf[blockIdx.x * SC_LANES + tid] = 0.f;   // h0 = 0
    }
    __syncthreads();

    // phase 3: re-scan with correct init, write h and output
    float h = sS[c][l];
    {
        size_t idx = (size_t)t0 * STRIDE + bd;
        #pragma unroll 4
        for (int s = 0; s < SC_LEN; ++s) {
            const float a = alpha[idx];
            const float v = hbuf[idx + STRIDE];
            h = fmaf(a, h, v);
            hbuf[idx + STRIDE] = h;
            alpha[idx] = h * h * sigmoidf_(h);
            idx += STRIDE;
        }
    }
}

extern "C" void kernel_launch(void* const* d_in, const int* in_sizes, int n_in,
                              void* d_out, int out_size, void* d_ws, size_t ws_size,
                              hipStream_t stream) {
    const float* x  = (const float*)d_in[0];
    const float* Wa = (const float*)d_in[1];
    const float* ba = (const float*)d_in[2];
    const float* Wv = (const float*)d_in[3];
    const float* bv = (const float*)d_in[4];
    float* out = (float*)d_out;

    dim3 grid(M_SZ / BM, N_SZ / BN);   // (128, 16)
    gemm_gates<<<grid, 256, 0, stream>>>(x, Wa, ba, Wv, bv, out);

    scan_hier<<<(B_SZ * D_SZ) / SC_LANES, 1024, 0, stream>>>(out);
}